// Round 2
// baseline (914.357 us; speedup 1.0000x reference)
//
#include <hip/hip_runtime.h>

// Problem constants (from setup_inputs; ey/ex/eh/ew are fixed by the harness)
// B=8, IN_CH=16, OUT_CH=32, GFC=64, x: 256x320, conv1 out: 96 ch @ 128x160
// prev_h/prev_c: 32 ch @ 256x320, crop: rows [0,128), cols [64,224)
#define NHID  5242880   // 8*32*128*160  (hidden)
#define NPREV 20971520  // 8*32*256*320  (new_h / new_c each)

__device__ __forceinline__ float sigm(float v) { return 1.0f / (1.0f + __expf(-v)); }

// ---------------------------------------------------------------------------
// Kernel A: per-(b,oc) gf dot products (full / row0 / col0 / corner) + zero the
// gf-mean accumulator (which lives in the new_gf slot of d_out).
// gfterm layout: [b][96][4] floats, stored at d_out[0..3071] (hidden region,
// fully overwritten later by conv2).
// ---------------------------------------------------------------------------
__global__ void gfprep_kernel(const float* __restrict__ gf,
                              const float* __restrict__ convw,
                              float* __restrict__ gfterm,
                              float* __restrict__ gfacc) {
  int t = blockIdx.x * 256 + threadIdx.x;
  if (t < 768) {
    int b = t / 96, o = t % 96;
    const float* g = gf + b * 64;
    float all = 0.f, row0 = 0.f, col0 = 0.f, corner = 0.f;
    for (int c = 0; c < 64; ++c) {
      const float* w = convw + (o * 80 + 16 + c) * 9;
      float w0 = w[0], w1 = w[1], w2 = w[2], w3 = w[3], w4 = w[4];
      float w5 = w[5], w6 = w[6], w7 = w[7], w8 = w[8];
      float gv = g[c];
      all    += gv * (w0 + w1 + w2 + w3 + w4 + w5 + w6 + w7 + w8);
      row0   += gv * (w0 + w1 + w2);   // taps reading input row -1 (ky==0)
      col0   += gv * (w0 + w3 + w6);   // taps reading input col -1 (kx==0)
      corner += gv * w0;
    }
    *reinterpret_cast<float4*>(gfterm + t * 4) = make_float4(all, row0, col0, corner);
  }
  int z = t - 768;
  if (z >= 0 && z < 512) gfacc[z] = 0.f;
}

// ---------------------------------------------------------------------------
// Kernel B: conv1 = tanh(conv3x3_s2(concat(x, gf_bcast)) + b).
// Tile: 16x32 outputs, thread = 2 px x 16 oc. oc groups 0..1 -> x_feat store,
// groups 2..5 -> gf channels, block-reduced into gfacc (for the spatial mean).
// ---------------------------------------------------------------------------
__global__ void conv1_kernel(const float* __restrict__ x,
                             const float* __restrict__ convw,
                             const float* __restrict__ convb,
                             const float* __restrict__ gfterm,
                             float* __restrict__ xfeat,
                             float* __restrict__ gfacc) {
  __shared__ float xs[4][33][67];   // 4 ic chunk, 33 rows, 65 cols (pitch 67)
  __shared__ float ws[4][9][16];    // [ic][tap][oc]
  __shared__ float red[4][16];
  const int tx = blockIdx.x, ty = blockIdx.y;
  const int b = blockIdx.z / 6, ocg = blockIdx.z % 6;
  const int ocb = ocg * 16;
  const int tid = threadIdx.x;
  const int r = tid >> 4, cc = tid & 15;

  float acc[2][16];
#pragma unroll
  for (int p = 0; p < 2; ++p)
#pragma unroll
    for (int o = 0; o < 16; ++o) acc[p][o] = 0.f;

  const int iy0 = ty * 32 - 1, ix0 = tx * 64 - 1;

  for (int icb = 0; icb < 16; icb += 4) {
    __syncthreads();
    // stage x tile (zero-fill the pad=1 border; upper bounds never exceeded)
    for (int e = tid; e < 4 * 33 * 65; e += 256) {
      int ic = e / (33 * 65);
      int rr = (e % (33 * 65)) / 65;
      int c2 = e % 65;
      int gy = iy0 + rr, gx = ix0 + c2;
      float v = 0.f;
      if (gy >= 0 && gx >= 0)
        v = x[((b * 16 + icb + ic) * 256 + gy) * 320 + gx];
      xs[ic][rr][c2] = v;
    }
    // stage weights [ic][tap][oc]
    for (int e = tid; e < 4 * 9 * 16; e += 256) {
      int o = e & 15, tap = (e >> 4) % 9, ic = e / 144;
      ws[ic][tap][o] = convw[((ocb + o) * 80 + icb + ic) * 9 + tap];
    }
    __syncthreads();

#pragma unroll
    for (int ic = 0; ic < 4; ++ic)
#pragma unroll
      for (int ky = 0; ky < 3; ++ky)
#pragma unroll
        for (int kx = 0; kx < 3; ++kx) {
          float wv[16];
#pragma unroll
          for (int q = 0; q < 4; ++q)
            *reinterpret_cast<float4*>(&wv[4 * q]) =
                *reinterpret_cast<const float4*>(&ws[ic][ky * 3 + kx][4 * q]);
          const float v0 = xs[ic][2 * r + ky][2 * cc + kx];
          const float v1 = xs[ic][2 * r + ky][2 * cc + 32 + kx];
#pragma unroll
          for (int o = 0; o < 16; ++o) {
            acc[0][o] = fmaf(v0, wv[o], acc[0][o]);
            acc[1][o] = fmaf(v1, wv[o], acc[1][o]);
          }
        }
  }

  const int oy = ty * 16 + r;
  if (ocg < 2) {
    // x_feat channels: store to staging area (new_h region of d_out)
#pragma unroll
    for (int p = 0; p < 2; ++p) {
      const int ox = tx * 32 + cc + p * 16;
#pragma unroll
      for (int o = 0; o < 16; ++o) {
        const int oc = ocb + o;
        const float4 tt = *reinterpret_cast<const float4*>(gfterm + (b * 96 + oc) * 4);
        float t = tt.x;
        if (oy == 0) t -= tt.y;
        if (ox == 0) t -= tt.z;
        if (oy == 0 && ox == 0) t += tt.w;
        float val = tanhf(acc[p][o] + convb[oc] + t);
        xfeat[((b * 32 + oc) * 128 + oy) * 160 + ox] = val;
      }
    }
  } else {
    // gf-update channels: tanh then block-reduce the spatial sum
    float s[16];
#pragma unroll
    for (int o = 0; o < 16; ++o) {
      const int oc = ocb + o;
      const float4 tt = *reinterpret_cast<const float4*>(gfterm + (b * 96 + oc) * 4);
      float sum = 0.f;
#pragma unroll
      for (int p = 0; p < 2; ++p) {
        const int ox = tx * 32 + cc + p * 16;
        float t = tt.x;
        if (oy == 0) t -= tt.y;
        if (ox == 0) t -= tt.z;
        if (oy == 0 && ox == 0) t += tt.w;
        sum += tanhf(acc[p][o] + convb[oc] + t);
      }
      s[o] = sum;
    }
#pragma unroll
    for (int o = 0; o < 16; ++o)
#pragma unroll
      for (int off = 1; off < 64; off <<= 1) s[o] += __shfl_xor(s[o], off);
    const int wid = tid >> 6, lane = tid & 63;
    if (lane == 0) {
#pragma unroll
      for (int o = 0; o < 16; ++o) red[wid][o] = s[o];
    }
    __syncthreads();
    if (tid < 16) {
      float tot = red[0][tid] + red[1][tid] + red[2][tid] + red[3][tid];
      atomicAdd(&gfacc[b * 64 + (ocb - 32) + tid], tot);
    }
  }
}

// ---------------------------------------------------------------------------
// Kernel C: new_gf = tanh(gf + mean). Accumulator is in-place in the new_gf
// slot of d_out.
// ---------------------------------------------------------------------------
__global__ void gffinal_kernel(const float* __restrict__ gf, float* __restrict__ gfout) {
  int i = blockIdx.x * 256 + threadIdx.x;
  if (i < 512) gfout[i] = tanhf(gf[i] + gfout[i] * (1.0f / 20480.0f));
}

// ---------------------------------------------------------------------------
// Kernel D: conv2 (gates) + fused LSTM elementwise.
// Tile 16x32 outputs; thread = 2 px x 8 logical ch x 4 gates (64 acc).
// Input ch 0..31 = x_feat (padded), 32..63 = h_pad:
//   h_pad(oy+ky, ox+kx) = 0 if oy+ky==0 else prev_h[oy+ky-1, 63+ox+kx].
// Writes hidden (d_out[0:NHID]) and cell into the new_c crop region directly.
// ---------------------------------------------------------------------------
__global__ void conv2_kernel(const float* __restrict__ xfeat,
                             const float* __restrict__ prevh,
                             const float* __restrict__ prevc,
                             const float* __restrict__ gatesw,
                             const float* __restrict__ gatesb,
                             float* __restrict__ out) {
  __shared__ float xs[8][18][35];   // [ic][row][col] (34 used, pitch 35)
  __shared__ float ws[8][9][32];    // [ic][tap][gate*8+l]
  const int tx = blockIdx.x, ty = blockIdx.y;
  const int b = blockIdx.z / 4, lg = blockIdx.z % 4;
  const int lb = lg * 8;
  const int tid = threadIdx.x;
  const int r = tid >> 4, cc = tid & 15;

  float acc[2][4][8];
#pragma unroll
  for (int p = 0; p < 2; ++p)
#pragma unroll
    for (int g = 0; g < 4; ++g)
#pragma unroll
      for (int l = 0; l < 8; ++l) acc[p][g][l] = 0.f;

  const int iy0 = ty * 16 - 1, ix0 = tx * 32 - 1;

  for (int icb = 0; icb < 64; icb += 8) {
    __syncthreads();
    // stage input tile: ic<32 from x_feat (zero pad), ic>=32 from prev_h
    // (row -1 is the zero top-pad; cols map to prev_h col gx+64, always valid)
    for (int e = tid; e < 8 * 18 * 34; e += 256) {
      int ic = e / 612;
      int rr = (e % 612) / 34;
      int c2 = e % 34;
      int gy = iy0 + rr, gx = ix0 + c2;
      int gic = icb + ic;
      float v = 0.f;
      if (gic < 32) {
        if (gy >= 0 && gy < 128 && gx >= 0 && gx < 160)
          v = xfeat[((b * 32 + gic) * 128 + gy) * 160 + gx];
      } else {
        if (gy >= 0)
          v = prevh[((b * 32 + (gic - 32)) * 256 + gy) * 320 + gx + 64];
      }
      xs[ic][rr][c2] = v;
    }
    // stage weights: [ic][tap][gate*8+l], oc = gate*32 + lb + l
    for (int e = tid; e < 8 * 9 * 32; e += 256) {
      int col = e & 31;
      int tap = (e >> 5) % 9;
      int ic = e / 288;
      int gate = col >> 3, l = col & 7;
      ws[ic][tap][col] = gatesw[((gate * 32 + lb + l) * 64 + icb + ic) * 9 + tap];
    }
    __syncthreads();

#pragma unroll 1
    for (int ic = 0; ic < 8; ++ic) {
#pragma unroll
      for (int ky = 0; ky < 3; ++ky)
#pragma unroll
        for (int kx = 0; kx < 3; ++kx) {
          float wv[32];
#pragma unroll
          for (int q = 0; q < 8; ++q)
            *reinterpret_cast<float4*>(&wv[4 * q]) =
                *reinterpret_cast<const float4*>(&ws[ic][ky * 3 + kx][4 * q]);
          const float v0 = xs[ic][r + ky][cc + kx];
          const float v1 = xs[ic][r + ky][cc + 16 + kx];
#pragma unroll
          for (int g = 0; g < 4; ++g)
#pragma unroll
            for (int l = 0; l < 8; ++l) {
              acc[0][g][l] = fmaf(v0, wv[g * 8 + l], acc[0][g][l]);
              acc[1][g][l] = fmaf(v1, wv[g * 8 + l], acc[1][g][l]);
            }
        }
    }
  }

  // fused LSTM epilogue: gates order ig, rg, og, cg
  const int oy = ty * 16 + r;
#pragma unroll
  for (int p = 0; p < 2; ++p) {
    const int ox = tx * 32 + cc + p * 16;
#pragma unroll
    for (int l = 0; l < 8; ++l) {
      const int ch = lb + l;
      float ig = acc[p][0][l] + gatesb[ch];
      float rg = acc[p][1][l] + gatesb[32 + ch];
      float og = acc[p][2][l] + gatesb[64 + ch];
      float cg = acc[p][3][l] + gatesb[96 + ch];
      float pc = prevc[((b * 32 + ch) * 256 + oy) * 320 + 64 + ox];
      float cell = sigm(rg) * pc + sigm(ig) * tanhf(cg);
      float hid = sigm(og) * tanhf(cell);
      out[((b * 32 + ch) * 128 + oy) * 160 + ox] = hid;                          // hidden
      out[NHID + NPREV + ((b * 32 + ch) * 256 + oy) * 320 + 64 + ox] = cell;     // new_c crop
    }
  }
}

// ---------------------------------------------------------------------------
// Kernel E: assemble new_h (full) and new_c (non-crop part; crop was written
// by conv2). One float4 per thread; the crop col range [64,224) is 4-aligned.
// ---------------------------------------------------------------------------
__global__ void assemble_kernel(const float* __restrict__ prevh,
                                const float* __restrict__ prevc,
                                float* __restrict__ out) {
  const int NPREV4 = NPREV / 4;
  int i = blockIdx.x * 256 + threadIdx.x;   // [0, 2*NPREV4)
  bool isC = i >= NPREV4;
  int j = isC ? i - NPREV4 : i;
  int flat = j * 4;
  int bch = flat / (256 * 320);
  int rem = flat % (256 * 320);
  int y = rem / 320, xc = rem % 320;
  bool inCrop = (y < 128) && (xc >= 64) && (xc < 224);
  if (!isC) {
    float4 v;
    if (inCrop)
      v = *reinterpret_cast<const float4*>(out + ((bch * 128 + y) * 160 + (xc - 64)));
    else
      v = *reinterpret_cast<const float4*>(prevh + flat);
    *reinterpret_cast<float4*>(out + NHID + flat) = v;
  } else {
    if (!inCrop)
      *reinterpret_cast<float4*>(out + NHID + NPREV + flat) =
          *reinterpret_cast<const float4*>(prevc + flat);
  }
}

// ---------------------------------------------------------------------------
extern "C" void kernel_launch(void* const* d_in, const int* in_sizes, int n_in,
                              void* d_out, int out_size, void* d_ws, size_t ws_size,
                              hipStream_t stream) {
  const float* x      = (const float*)d_in[0];
  const float* prevh  = (const float*)d_in[1];
  const float* prevc  = (const float*)d_in[2];
  const float* gf     = (const float*)d_in[3];
  const float* convw  = (const float*)d_in[4];
  const float* convb  = (const float*)d_in[5];
  const float* gatesw = (const float*)d_in[6];
  const float* gatesb = (const float*)d_in[7];
  float* out = (float*)d_out;

  float* gfterm = out;                       // [8][96][4], hidden region (overwritten by conv2)
  float* xfeat  = out + NHID;                // x_feat staging in new_h region (overwritten by assemble)
  float* gfacc  = out + NHID + 2 * (size_t)NPREV;  // new_gf slot doubles as mean accumulator

  gfprep_kernel<<<5, 256, 0, stream>>>(gf, convw, gfterm, gfacc);
  conv1_kernel<<<dim3(5, 8, 48), 256, 0, stream>>>(x, convw, convb, gfterm, xfeat, gfacc);
  gffinal_kernel<<<2, 256, 0, stream>>>(gf, gfacc);
  conv2_kernel<<<dim3(5, 8, 32), 256, 0, stream>>>(xfeat, prevh, prevc, gatesw, gatesb, out);
  assemble_kernel<<<2 * (NPREV / 4) / 256, 256, 0, stream>>>(prevh, prevc, out);
}